// Round 1
// baseline (586.172 us; speedup 1.0000x reference)
//
#include <hip/hip_runtime.h>

#define N_NODES 50000
#define N_EDGES 800000
#define HEADS 8
#define FOUT 32
#define HF 256   // HEADS*FOUT
#define IN_F 256
#define EDGE_F 64

// ---------------- GEMM: Wh = h @ W_w   (M=50000, K=256, N=256) ----------------
#define BM 64
#define BN 64
#define BK 16

__global__ __launch_bounds__(256) void k_gemm(
    const float* __restrict__ A, const float* __restrict__ B,
    float* __restrict__ C, int M)
{
  __shared__ float As[BK][BM + 4];   // transposed A tile, +4 pad (keeps 16B align, breaks conflicts)
  __shared__ float Bs[BK][BN + 4];
  const int tid = threadIdx.x;
  const int m0 = blockIdx.x * BM;
  const int n0 = blockIdx.y * BN;
  const int tx = tid & 15;
  const int ty = tid >> 4;
  const int a_r = tid >> 2;             // 0..63
  const int a_c = (tid & 3) << 2;       // 0,4,8,12
  const int b_r = tid >> 4;             // 0..15
  const int b_c = (tid & 15) << 2;      // 0..60
  const int arow = m0 + a_r;
  float acc[4][4] = {};

  for (int k0 = 0; k0 < IN_F; k0 += BK) {
    float4 av = make_float4(0.f, 0.f, 0.f, 0.f);
    if (arow < M) av = *(const float4*)&A[arow * IN_F + k0 + a_c];
    As[a_c + 0][a_r] = av.x;
    As[a_c + 1][a_r] = av.y;
    As[a_c + 2][a_r] = av.z;
    As[a_c + 3][a_r] = av.w;
    *(float4*)&Bs[b_r][b_c] = *(const float4*)&B[(k0 + b_r) * HF + n0 + b_c];
    __syncthreads();
#pragma unroll
    for (int k = 0; k < BK; ++k) {
      float4 a4 = *(const float4*)&As[k][ty << 2];
      float4 b4 = *(const float4*)&Bs[k][tx << 2];
      float avv[4] = {a4.x, a4.y, a4.z, a4.w};
      float bvv[4] = {b4.x, b4.y, b4.z, b4.w};
#pragma unroll
      for (int i = 0; i < 4; ++i)
#pragma unroll
        for (int j = 0; j < 4; ++j)
          acc[i][j] = fmaf(avv[i], bvv[j], acc[i][j]);
    }
    __syncthreads();
  }
#pragma unroll
  for (int i = 0; i < 4; ++i) {
    int row = m0 + (ty << 2) + i;
    if (row < M)
      *(float4*)&C[row * HF + n0 + (tx << 2)] =
          make_float4(acc[i][0], acc[i][1], acc[i][2], acc[i][3]);
  }
}

// ---------------- alpha_src/dst[n,h] = <Wh[n,h,:], a_src/dst[h,:]> ----------------
__global__ __launch_bounds__(256) void k_alpha(
    const float* __restrict__ Wh, const float* __restrict__ a_src,
    const float* __restrict__ a_dst, float* __restrict__ out_s,
    float* __restrict__ out_d)
{
  int idx = blockIdx.x * 256 + threadIdx.x;   // n*8+h
  if (idx >= N_NODES * HEADS) return;
  int h = idx & 7;
  int n = idx >> 3;
  const float4* row = (const float4*)&Wh[n * HF + h * FOUT];
  const float4* u4 = (const float4*)&a_src[h * FOUT];
  const float4* v4 = (const float4*)&a_dst[h * FOUT];
  float s1 = 0.f, s2 = 0.f;
#pragma unroll
  for (int q = 0; q < FOUT / 4; ++q) {
    float4 w = row[q];
    float4 u = u4[q];
    float4 v = v4[q];
    s1 += w.x * u.x + w.y * u.y + w.z * u.z + w.w * u.w;
    s2 += w.x * v.x + w.y * v.y + w.z * v.z + w.w * v.w;
  }
  out_s[idx] = s1;
  out_d[idx] = s2;
}

// ---------------- B[k,h] = sum_f We_w[k, h*32+f] * a_edge[h,f]  (64x8) ----------------
__global__ __launch_bounds__(256) void k_bmat(
    const float* __restrict__ We_w, const float* __restrict__ a_edge,
    float* __restrict__ Bmat)
{
  int i = blockIdx.x * 256 + threadIdx.x;
  if (i >= EDGE_F * HEADS) return;
  int k = i >> 3, h = i & 7;
  float s = 0.f;
#pragma unroll
  for (int f = 0; f < FOUT; ++f)
    s += We_w[k * HF + h * FOUT + f] * a_edge[h * FOUT + f];
  Bmat[i] = s;   // layout [k][h]
}

// ---------------- degree histogram ----------------
__global__ __launch_bounds__(256) void k_hist(const int* __restrict__ dst,
                                              int* __restrict__ deg)
{
  int e = blockIdx.x * 256 + threadIdx.x;
  if (e < N_EDGES) atomicAdd(&deg[dst[e]], 1);
}

// ---------------- single-block exclusive scan -> offsets, cursor ----------------
__global__ __launch_bounds__(1024) void k_scan(const int* __restrict__ deg,
                                               int* __restrict__ offsets,
                                               int* __restrict__ cursor)
{
  __shared__ int tmp[1024];
  __shared__ int s_carry;
  int t = threadIdx.x;
  if (t == 0) s_carry = 0;
  __syncthreads();
  for (int base = 0; base < N_NODES; base += 1024) {
    int i = base + t;
    int v = (i < N_NODES) ? deg[i] : 0;
    tmp[t] = v;
    __syncthreads();
    int x = tmp[t];
    for (int off = 1; off < 1024; off <<= 1) {
      int y = (t >= off) ? tmp[t - off] : 0;
      __syncthreads();
      x += y;
      tmp[t] = x;
      __syncthreads();
    }
    int carry = s_carry;
    int incl = x + carry;
    if (i < N_NODES) {
      offsets[i] = incl - v;
      cursor[i] = incl - v;
    }
    __syncthreads();              // all threads read s_carry before update
    if (t == 1023) s_carry = incl;
    __syncthreads();
  }
  if (t == 0) offsets[N_NODES] = s_carry;
}

// ---------------- edge logits + leaky relu, scattered into dst-sorted order ----------------
__global__ __launch_bounds__(256) void k_logits(
    const float* __restrict__ ef, const int* __restrict__ src,
    const int* __restrict__ dst, const float* __restrict__ alpha_s,
    const float* __restrict__ alpha_d, const float* __restrict__ Bmat,
    int* __restrict__ cursor, float* __restrict__ s_sorted,
    int* __restrict__ src_srt)
{
  __shared__ float Bs[EDGE_F * HEADS];
  for (int i = threadIdx.x; i < EDGE_F * HEADS; i += 256) Bs[i] = Bmat[i];
  __syncthreads();
  int e = blockIdx.x * 256 + threadIdx.x;
  if (e >= N_EDGES) return;
  int sn = src[e], dn = dst[e];
  float sc[8];
  {
    const float4* a1 = (const float4*)&alpha_s[sn * 8];
    const float4* a2 = (const float4*)&alpha_d[dn * 8];
    float4 p = a1[0], q = a1[1], r = a2[0], w = a2[1];
    sc[0] = p.x + r.x; sc[1] = p.y + r.y; sc[2] = p.z + r.z; sc[3] = p.w + r.w;
    sc[4] = q.x + w.x; sc[5] = q.y + w.y; sc[6] = q.z + w.z; sc[7] = q.w + w.w;
  }
  const float4* efr = (const float4*)&ef[e * EDGE_F];
  for (int g = 0; g < EDGE_F / 4; ++g) {
    float4 v = efr[g];
    const float* b0 = &Bs[(g * 4) * 8];
#pragma unroll
    for (int hh = 0; hh < 8; ++hh)
      sc[hh] += v.x * b0[hh] + v.y * b0[8 + hh] + v.z * b0[16 + hh] + v.w * b0[24 + hh];
  }
#pragma unroll
  for (int hh = 0; hh < 8; ++hh)
    sc[hh] = sc[hh] > 0.f ? sc[hh] : 0.01f * sc[hh];
  int p = atomicAdd(&cursor[dn], 1);
  float4* o = (float4*)&s_sorted[p * 8];
  o[0] = make_float4(sc[0], sc[1], sc[2], sc[3]);
  o[1] = make_float4(sc[4], sc[5], sc[6], sc[7]);
  src_srt[p] = sn;
}

// ---------------- per-node segment softmax + weighted gather-sum + ELU ----------------
__global__ __launch_bounds__(256) void k_agg(
    const float* __restrict__ s_sorted, const int* __restrict__ src_srt,
    const int* __restrict__ offsets, const float* __restrict__ Wh,
    float* __restrict__ out)
{
  int n = blockIdx.x;
  int beg = offsets[n], end = offsets[n + 1];
  int t = threadIdx.x;
  int h = t >> 5;      // head
  int j = t & 31;      // lane-in-head == output feature f
  __shared__ float mh[HEADS], dh[HEADS];

  // pass A: per-head max over incoming edges
  float m = -3.0e38f;
  for (int i = beg + j; i < end; i += 32)
    m = fmaxf(m, s_sorted[i * 8 + h]);
#pragma unroll
  for (int off = 16; off > 0; off >>= 1)
    m = fmaxf(m, __shfl_xor(m, off, 32));
  if (j == 0) mh[h] = m;
  __syncthreads();
  float mx = mh[h];

  // pass B: per-head denominator
  float d = 0.f;
  for (int i = beg + j; i < end; i += 32)
    d += __expf(s_sorted[i * 8 + h] - mx);
#pragma unroll
  for (int off = 16; off > 0; off >>= 1)
    d += __shfl_xor(d, off, 32);
  if (j == 0) dh[h] = (d > 0.f) ? 1.0f / d : 0.f;
  __syncthreads();
  float inv = dh[h];

  // pass C: weighted gather-sum of Wh rows
  float acc = 0.f;
  for (int i = beg; i < end; ++i) {
    float w = __expf(s_sorted[i * 8 + h] - mx) * inv;
    acc = fmaf(w, Wh[src_srt[i] * HF + t], acc);
  }
  // fused ELU
  out[n * HF + t] = acc > 0.f ? acc : expm1f(acc);
}

extern "C" void kernel_launch(void* const* d_in, const int* in_sizes, int n_in,
                              void* d_out, int out_size, void* d_ws, size_t ws_size,
                              hipStream_t stream)
{
  const float* h    = (const float*)d_in[0];
  const float* ef   = (const float*)d_in[1];
  const int*   src  = (const int*)d_in[2];
  const int*   dst  = (const int*)d_in[3];
  const float* W_w  = (const float*)d_in[4];
  const float* We_w = (const float*)d_in[5];
  const float* a_s  = (const float*)d_in[6];
  const float* a_d  = (const float*)d_in[7];
  const float* a_e  = (const float*)d_in[8];
  float* out = (float*)d_out;

  char* ws = (char*)d_ws;
  size_t off = 0;
  auto take = [&](size_t bytes) {
    char* p = ws + off;
    off += (bytes + 255) & ~(size_t)255;
    return p;
  };
  float* Wh       = (float*)take((size_t)N_NODES * HF * 4);          // 51.2 MB
  float* s_sorted = (float*)take((size_t)N_EDGES * HEADS * 4);       // 25.6 MB
  float* alpha_s  = (float*)take((size_t)N_NODES * HEADS * 4);       // 1.6 MB
  float* alpha_d  = (float*)take((size_t)N_NODES * HEADS * 4);       // 1.6 MB
  int*   src_srt  = (int*)take((size_t)N_EDGES * 4);                 // 3.2 MB
  int*   deg      = (int*)take((size_t)N_NODES * 4);
  int*   offs     = (int*)take((size_t)(N_NODES + 1) * 4);
  int*   cursor   = (int*)take((size_t)N_NODES * 4);
  float* Bmat     = (float*)take((size_t)EDGE_F * HEADS * 4);

  hipMemsetAsync(deg, 0, N_NODES * sizeof(int), stream);
  k_hist<<<(N_EDGES + 255) / 256, 256, 0, stream>>>(dst, deg);
  k_scan<<<1, 1024, 0, stream>>>(deg, offs, cursor);
  k_bmat<<<(EDGE_F * HEADS + 255) / 256, 256, 0, stream>>>(We_w, a_e, Bmat);
  k_gemm<<<dim3((N_NODES + BM - 1) / BM, HF / BN), 256, 0, stream>>>(h, W_w, Wh, N_NODES);
  k_alpha<<<(N_NODES * HEADS + 255) / 256, 256, 0, stream>>>(Wh, a_s, a_d, alpha_s, alpha_d);
  k_logits<<<(N_EDGES + 255) / 256, 256, 0, stream>>>(ef, src, dst, alpha_s, alpha_d,
                                                      Bmat, cursor, s_sorted, src_srt);
  k_agg<<<N_NODES, 256, 0, stream>>>(s_sorted, src_srt, offs, Wh, out);
}

// Round 2
// 495.394 us; speedup vs baseline: 1.1832x; 1.1832x over previous
//
#include <hip/hip_runtime.h>

#define N_NODES 50000
#define N_EDGES 800000
#define HEADS 8
#define FOUT 32
#define HF 256   // HEADS*FOUT
#define IN_F 256
#define EDGE_F 64

typedef __attribute__((ext_vector_type(8))) short bf16x8;
typedef __attribute__((ext_vector_type(4))) float f32x4;

__device__ inline ushort f2bf(float f) {  // round-to-nearest-even f32 -> bf16
  unsigned u = __float_as_uint(f);
  unsigned r = 0x7FFFu + ((u >> 16) & 1u);
  return (ushort)((u + r) >> 16);
}

// ---------------- convert h -> bf16 (8 elems/thread, 16B stores) ----------------
__global__ __launch_bounds__(256) void k_cvtH(const float* __restrict__ in,
                                              ushort* __restrict__ out, int n)
{
  int i = (blockIdx.x * 256 + threadIdx.x) * 8;
  if (i >= n) return;
  float4 a = *(const float4*)&in[i];
  float4 b = *(const float4*)&in[i + 4];
  uint4 o;
  o.x = (unsigned)f2bf(a.x) | ((unsigned)f2bf(a.y) << 16);
  o.y = (unsigned)f2bf(a.z) | ((unsigned)f2bf(a.w) << 16);
  o.z = (unsigned)f2bf(b.x) | ((unsigned)f2bf(b.y) << 16);
  o.w = (unsigned)f2bf(b.z) | ((unsigned)f2bf(b.w) << 16);
  *(uint4*)&out[i] = o;
}

// ---------------- convert + transpose W: Wt[n][k] = bf16(W[k][n]) ----------------
__global__ __launch_bounds__(256) void k_cvtW(const float* __restrict__ W,
                                              ushort* __restrict__ Wt)
{
  int i = blockIdx.x * 256 + threadIdx.x;   // output index, coalesced write
  int n = i >> 8, k = i & 255;
  Wt[i] = f2bf(W[k * HF + n]);
}

// ---------------- GEMM: Wh = h @ W  via bf16 MFMA. Block: 64 rows x all 256 cols ----------------
// 4 waves, wave w owns cols [w*64, w*64+64). LDS stride 40 bf16 (80B) -> 2-way (free) conflicts.
__global__ __launch_bounds__(256) void k_gemm_bf16(
    const ushort* __restrict__ hb,   // [M][256] bf16, K-contig
    const ushort* __restrict__ Wt,   // [256 n][256 k] bf16, K-contig
    float* __restrict__ C, int M)
{
  __shared__ ushort As[64 * 40];
  __shared__ ushort Bs[256 * 40];
  const int tid = threadIdx.x;
  const int wave = tid >> 6, lane = tid & 63;
  const int m0 = blockIdx.x * 64;
  const int row16 = lane & 15;
  const int kg = lane >> 4;        // k-group 0..3 -> k offset kg*8
  f32x4 acc[4][4] = {};

  const int a_r = tid >> 2;              // 0..63
  const int a_c = (tid & 3) * 8;         // bf16 col 0,8,16,24
  const int a_row = m0 + a_r;

  for (int k0 = 0; k0 < IN_F; k0 += 32) {
    uint4 av = make_uint4(0, 0, 0, 0);
    if (a_row < M) av = *(const uint4*)&hb[(size_t)a_row * IN_F + k0 + a_c];
    *(uint4*)&As[a_r * 40 + a_c] = av;
    const uint4* bp = (const uint4*)&Wt[(size_t)tid * IN_F + k0];
    uint4 b0 = bp[0], b1 = bp[1], b2 = bp[2], b3 = bp[3];
    *(uint4*)&Bs[tid * 40 + 0]  = b0;
    *(uint4*)&Bs[tid * 40 + 8]  = b1;
    *(uint4*)&Bs[tid * 40 + 16] = b2;
    *(uint4*)&Bs[tid * 40 + 24] = b3;
    __syncthreads();
    bf16x8 af[4], bfr[4];
#pragma unroll
    for (int mi = 0; mi < 4; ++mi)
      af[mi] = *(const bf16x8*)&As[(mi * 16 + row16) * 40 + kg * 8];
#pragma unroll
    for (int ni = 0; ni < 4; ++ni)
      bfr[ni] = *(const bf16x8*)&Bs[(wave * 64 + ni * 16 + row16) * 40 + kg * 8];
#pragma unroll
    for (int mi = 0; mi < 4; ++mi)
#pragma unroll
      for (int ni = 0; ni < 4; ++ni)
        acc[mi][ni] = __builtin_amdgcn_mfma_f32_16x16x32_bf16(af[mi], bfr[ni], acc[mi][ni], 0, 0, 0);
    __syncthreads();
  }
  // C/D layout (m89-verified): col = lane&15, row = (lane>>4)*4 + reg
#pragma unroll
  for (int mi = 0; mi < 4; ++mi) {
#pragma unroll
    for (int r = 0; r < 4; ++r) {
      int row = m0 + mi * 16 + kg * 4 + r;
      if (row < M) {
#pragma unroll
        for (int ni = 0; ni < 4; ++ni)
          C[(size_t)row * HF + wave * 64 + ni * 16 + row16] = acc[mi][ni][r];
      }
    }
  }
}

// ---------------- alpha_src/dst[n,h] = <Wh[n,h,:], a_src/dst[h,:]> ----------------
__global__ __launch_bounds__(256) void k_alpha(
    const float* __restrict__ Wh, const float* __restrict__ a_src,
    const float* __restrict__ a_dst, float* __restrict__ out_s,
    float* __restrict__ out_d)
{
  int idx = blockIdx.x * 256 + threadIdx.x;   // n*8+h
  if (idx >= N_NODES * HEADS) return;
  int h = idx & 7;
  int n = idx >> 3;
  const float4* row = (const float4*)&Wh[n * HF + h * FOUT];
  const float4* u4 = (const float4*)&a_src[h * FOUT];
  const float4* v4 = (const float4*)&a_dst[h * FOUT];
  float s1 = 0.f, s2 = 0.f;
#pragma unroll
  for (int q = 0; q < FOUT / 4; ++q) {
    float4 w = row[q];
    float4 u = u4[q];
    float4 v = v4[q];
    s1 += w.x * u.x + w.y * u.y + w.z * u.z + w.w * u.w;
    s2 += w.x * v.x + w.y * v.y + w.z * v.z + w.w * v.w;
  }
  out_s[idx] = s1;
  out_d[idx] = s2;
}

// ---------------- B[k,h] = sum_f We_w[k, h*32+f] * a_edge[h,f]  (64x8) ----------------
__global__ __launch_bounds__(256) void k_bmat(
    const float* __restrict__ We_w, const float* __restrict__ a_edge,
    float* __restrict__ Bmat)
{
  int i = blockIdx.x * 256 + threadIdx.x;
  if (i >= EDGE_F * HEADS) return;
  int k = i >> 3, h = i & 7;
  float s = 0.f;
#pragma unroll
  for (int f = 0; f < FOUT; ++f)
    s += We_w[k * HF + h * FOUT + f] * a_edge[h * FOUT + f];
  Bmat[i] = s;   // layout [k][h]
}

// ---------------- degree histogram ----------------
__global__ __launch_bounds__(256) void k_hist(const int* __restrict__ dst,
                                              int* __restrict__ deg)
{
  int e = blockIdx.x * 256 + threadIdx.x;
  if (e < N_EDGES) atomicAdd(&deg[dst[e]], 1);
}

// ---------------- exclusive scan: thread-serial chunks + one block scan ----------------
#define SCAN_ITEMS 49   // 1024*49 = 50176 >= N_NODES
__global__ __launch_bounds__(1024) void k_scan(const int* __restrict__ deg,
                                               int* __restrict__ offsets,
                                               int* __restrict__ cursor)
{
  __shared__ int sums[1024];
  int t = threadIdx.x;
  int base = t * SCAN_ITEMS;
  int s = 0;
  for (int i = 0; i < SCAN_ITEMS; ++i) {
    int idx = base + i;
    if (idx < N_NODES) s += deg[idx];
  }
  sums[t] = s;
  __syncthreads();
  int x = s;
  for (int off = 1; off < 1024; off <<= 1) {
    int y = (t >= off) ? sums[t - off] : 0;
    __syncthreads();
    x += y;
    sums[t] = x;
    __syncthreads();
  }
  int run = x - s;   // exclusive prefix of this thread's chunk
  for (int i = 0; i < SCAN_ITEMS; ++i) {
    int idx = base + i;
    if (idx < N_NODES) {
      offsets[idx] = run;
      cursor[idx] = run;
      run += deg[idx];
    }
  }
  if (t == 1023) offsets[N_NODES] = x;
}

// ---------------- edge logits + leaky relu, scattered into dst-sorted order ----------------
__global__ __launch_bounds__(256) void k_logits(
    const float* __restrict__ ef, const int* __restrict__ src,
    const int* __restrict__ dst, const float* __restrict__ alpha_s,
    const float* __restrict__ alpha_d, const float* __restrict__ Bmat,
    int* __restrict__ cursor, float* __restrict__ s_sorted,
    int* __restrict__ src_srt)
{
  __shared__ float Bs[EDGE_F * HEADS];
  for (int i = threadIdx.x; i < EDGE_F * HEADS; i += 256) Bs[i] = Bmat[i];
  __syncthreads();
  int e = blockIdx.x * 256 + threadIdx.x;
  if (e >= N_EDGES) return;
  int sn = src[e], dn = dst[e];
  float sc[8];
  {
    const float4* a1 = (const float4*)&alpha_s[sn * 8];
    const float4* a2 = (const float4*)&alpha_d[dn * 8];
    float4 p = a1[0], q = a1[1], r = a2[0], w = a2[1];
    sc[0] = p.x + r.x; sc[1] = p.y + r.y; sc[2] = p.z + r.z; sc[3] = p.w + r.w;
    sc[4] = q.x + w.x; sc[5] = q.y + w.y; sc[6] = q.z + w.z; sc[7] = q.w + w.w;
  }
  const float4* efr = (const float4*)&ef[e * EDGE_F];
  for (int g = 0; g < EDGE_F / 4; ++g) {
    float4 v = efr[g];
    const float* b0 = &Bs[(g * 4) * 8];
#pragma unroll
    for (int hh = 0; hh < 8; ++hh)
      sc[hh] += v.x * b0[hh] + v.y * b0[8 + hh] + v.z * b0[16 + hh] + v.w * b0[24 + hh];
  }
#pragma unroll
  for (int hh = 0; hh < 8; ++hh)
    sc[hh] = sc[hh] > 0.f ? sc[hh] : 0.01f * sc[hh];
  int p = atomicAdd(&cursor[dn], 1);
  float4* o = (float4*)&s_sorted[p * 8];
  o[0] = make_float4(sc[0], sc[1], sc[2], sc[3]);
  o[1] = make_float4(sc[4], sc[5], sc[6], sc[7]);
  src_srt[p] = sn;
}

// ---------------- per-node segment softmax + weighted gather-sum + ELU ----------------
// Weights computed ONCE per (edge,head) into LDS; inner loop = broadcast LDS read + gather + fma.
__global__ __launch_bounds__(256) void k_agg(
    const float* __restrict__ s_sorted, const int* __restrict__ src_srt,
    const int* __restrict__ offsets, const float* __restrict__ Wh,
    float* __restrict__ out)
{
  int n = blockIdx.x;
  int beg = offsets[n], end = offsets[n + 1];
  int t = threadIdx.x;
  int h = t >> 5;      // head
  int j = t & 31;      // lane-in-head == output feature f / edge slot
  __shared__ float mh[HEADS], dh[HEADS];
  __shared__ int s_idx[32];
  __shared__ float s_w[32 * 8];   // [edge][head]

  // pass A: per-head max over incoming edges
  float m = -3.0e38f;
  for (int i = beg + j; i < end; i += 32)
    m = fmaxf(m, s_sorted[i * 8 + h]);
#pragma unroll
  for (int off = 16; off > 0; off >>= 1)
    m = fmaxf(m, __shfl_xor(m, off, 32));
  if (j == 0) mh[h] = m;
  __syncthreads();
  float mx = mh[h];

  // pass B: per-head denominator
  float d = 0.f;
  for (int i = beg + j; i < end; i += 32)
    d += __expf(s_sorted[i * 8 + h] - mx);
#pragma unroll
  for (int off = 16; off > 0; off >>= 1)
    d += __shfl_xor(d, off, 32);
  if (j == 0) dh[h] = (d > 0.f) ? 1.0f / d : 0.f;
  __syncthreads();
  float inv = dh[h];

  // pass C: chunks of 32 edges; stage idx + weights in LDS
  float acc = 0.f;
  for (int c0 = beg; c0 < end; c0 += 32) {
    int cnt = end - c0; cnt = cnt < 32 ? cnt : 32;
    if (t < cnt) s_idx[t] = src_srt[c0 + t];
    if (j < cnt) s_w[j * 8 + h] = __expf(s_sorted[(c0 + j) * 8 + h] - mx) * inv;
    __syncthreads();
    for (int k = 0; k < cnt; ++k)
      acc = fmaf(s_w[k * 8 + h], Wh[(size_t)s_idx[k] * HF + t], acc);
    __syncthreads();
  }
  out[n * HF + t] = acc > 0.f ? acc : expm1f(acc);
}

extern "C" void kernel_launch(void* const* d_in, const int* in_sizes, int n_in,
                              void* d_out, int out_size, void* d_ws, size_t ws_size,
                              hipStream_t stream)
{
  const float* h    = (const float*)d_in[0];
  const float* ef   = (const float*)d_in[1];
  const int*   src  = (const int*)d_in[2];
  const int*   dst  = (const int*)d_in[3];
  const float* W_w  = (const float*)d_in[4];
  const float* We_w = (const float*)d_in[5];
  const float* a_s  = (const float*)d_in[6];
  const float* a_d  = (const float*)d_in[7];
  const float* a_e  = (const float*)d_in[8];
  float* out = (float*)d_out;

  char* ws = (char*)d_ws;
  size_t off = 0;
  auto take = [&](size_t bytes) {
    char* p = ws + off;
    off += (bytes + 255) & ~(size_t)255;
    return p;
  };
  float* Wh       = (float*)take((size_t)N_NODES * HF * 4);          // 51.2 MB
  float* s_sorted = (float*)take((size_t)N_EDGES * HEADS * 4);       // 25.6 MB (aliased w/ hb)
  float* alpha_s  = (float*)take((size_t)N_NODES * HEADS * 4);
  float* alpha_d  = (float*)take((size_t)N_NODES * HEADS * 4);
  int*   src_srt  = (int*)take((size_t)N_EDGES * 4);
  int*   deg      = (int*)take((size_t)N_NODES * 4);
  int*   offs     = (int*)take((size_t)(N_NODES + 1) * 4);
  int*   cursor   = (int*)take((size_t)N_NODES * 4);
  float* Bmat     = (float*)take((size_t)EDGE_F * HEADS * 4);
  ushort* Wt      = (ushort*)take((size_t)HF * IN_F * 2);            // 128 KB

  // hb (bf16 h, 25.6 MB) aliases s_sorted: hb is dead after k_gemm_bf16,
  // s_sorted is first written by k_logits which runs strictly after (same stream).
  ushort* hb = (ushort*)s_sorted;

  hipMemsetAsync(deg, 0, N_NODES * sizeof(int), stream);
  k_hist<<<(N_EDGES + 255) / 256, 256, 0, stream>>>(dst, deg);
  k_scan<<<1, 1024, 0, stream>>>(deg, offs, cursor);
  k_bmat<<<(EDGE_F * HEADS + 255) / 256, 256, 0, stream>>>(We_w, a_e, Bmat);
  k_cvtH<<<(N_NODES * IN_F / 8 + 255) / 256, 256, 0, stream>>>(h, hb, N_NODES * IN_F);
  k_cvtW<<<(HF * IN_F) / 256, 256, 0, stream>>>(W_w, Wt);
  k_gemm_bf16<<<(N_NODES + 63) / 64, 256, 0, stream>>>(hb, Wt, Wh, N_NODES);
  k_alpha<<<(N_NODES * HEADS + 255) / 256, 256, 0, stream>>>(Wh, a_s, a_d, alpha_s, alpha_d);
  k_logits<<<(N_EDGES + 255) / 256, 256, 0, stream>>>(ef, src, dst, alpha_s, alpha_d,
                                                      Bmat, cursor, s_sorted, src_srt);
  k_agg<<<N_NODES, 256, 0, stream>>>(s_sorted, src_srt, offs, Wh, out);
}